// Round 4
// baseline (1141.784 us; speedup 1.0000x reference)
//
#include <hip/hip_runtime.h>
#include <hip/hip_cooperative_groups.h>
#include <math.h>

namespace cg = cooperative_groups;

// Problem geometry (fixed by the reference)
#define BB 8
#define CC 256
#define HWSZ 36864            // floats per (b,c) slice
#define QF 9216               // floats per quarter slice
#define INTERNAL 16
#define NBLK 512              // 2 blocks/CU needed; ~4/CU capacity -> margin
#define TPB 256
#define ITT 18                // float4 per thread per phase (half slice = 4608 float4)

// ---------------- fused single-read cooperative kernel ----------------
// Each block owns channel c = blk>>1, half h = blk&1 (quarters 2h,2h+1 —
// contiguous 18432 floats). Per batch phase:
//   A: load 18 float4 into registers, sumsq -> pbuf[b][blk]
//   grid.sync()
//   B: gate MLP from 512 partials (redundant per block), scale regs, store.
// The input tensor is read from HBM exactly once.
__global__ __launch_bounds__(TPB, 2) void se_fused_kernel(
    const float* __restrict__ in, float* __restrict__ out,
    float* __restrict__ pbuf,          // [BB][NBLK]
    const float* __restrict__ w_down,  // [16, 256]
    const float* __restrict__ b_down,  // [16]
    const float* __restrict__ w_up,    // [256, 16]
    const float* __restrict__ b_up)    // [256]
{
    cg::grid_group grid = cg::this_grid();
    const int blk = blockIdx.x;
    const int c   = blk >> 1;
    const int h   = blk & 1;
    const int tid = threadIdx.x;
    const int lane = tid & 63, wave = tid >> 6;

    __shared__ float xs[CC];
    __shared__ float hs[INTERNAL];
    __shared__ float red[4];
    __shared__ float gsh;

    for (int b = 0; b < BB; ++b) {
        // ---- phase A: register-stage + sum of squares ----
        const float4* p = reinterpret_cast<const float4*>(
            in + ((size_t)(b * CC + c) * HWSZ) + (size_t)h * 2 * QF);
        float4 v[ITT];
        float acc = 0.f;
        #pragma unroll
        for (int i = 0; i < ITT; ++i) {
            v[i] = p[tid + i * TPB];
            acc += v[i].x * v[i].x + v[i].y * v[i].y
                 + v[i].z * v[i].z + v[i].w * v[i].w;
        }
        for (int off = 32; off > 0; off >>= 1)
            acc += __shfl_down(acc, off, 64);
        if (lane == 0) red[wave] = acc;
        __syncthreads();
        if (tid == 0)
            pbuf[(size_t)b * NBLK + blk] = red[0] + red[1] + red[2] + red[3];
        __threadfence();
        grid.sync();

        // ---- phase B: gate MLP ----
        {
            // channel tid's two half-partials are pbuf[b][2*tid], pbuf[b][2*tid+1]
            float2 pp = reinterpret_cast<const float2*>(
                pbuf + (size_t)b * NBLK)[tid];
            float g = sqrtf(pp.x + pp.y);
            xs[tid] = g / (g + 1e-6f);
        }
        __syncthreads();
        {
            const int j = tid >> 4, l = tid & 15;
            const float* wr = w_down + j * CC;
            float a = 0.f;
            #pragma unroll
            for (int k = 0; k < CC / 16; ++k)
                a += xs[l + k * 16] * wr[l + k * 16];
            a += __shfl_down(a, 8, 16);
            a += __shfl_down(a, 4, 16);
            a += __shfl_down(a, 2, 16);
            a += __shfl_down(a, 1, 16);
            if (l == 0) hs[j] = fmaxf(a + b_down[j], 0.f);
        }
        __syncthreads();
        if (tid == 0) {
            float a = b_up[c];
            const float* wu = w_up + c * INTERNAL;
            #pragma unroll
            for (int j = 0; j < INTERNAL; ++j) a += hs[j] * wu[j];
            gsh = 1.f / (1.f + expf(-a));
        }
        __syncthreads();

        // ---- scale register-resident data and store ----
        const float gv = gsh;
        float4* po = reinterpret_cast<float4*>(
            out + ((size_t)(b * CC + c) * HWSZ) + (size_t)h * 2 * QF);
        #pragma unroll
        for (int i = 0; i < ITT; ++i) {
            float4 w = v[i];
            w.x *= gv; w.y *= gv; w.z *= gv; w.w *= gv;
            po[tid + i * TPB] = w;
        }
        // LDS reuse across phases is ordered by grid.sync (full block barrier)
        // plus the __syncthreads chain above.
    }
}

// ---------------- fallback path (proven R1 kernels) ----------------
#define HW4 (HWSZ / 4)

__global__ __launch_bounds__(256) void se_sumsq_kernel(
    const float* __restrict__ in, float* __restrict__ sumsq)
{
    const int bc = blockIdx.x;
    const float4* p = reinterpret_cast<const float4*>(in + (size_t)bc * HWSZ);
    float acc = 0.f;
    #pragma unroll 4
    for (int i = threadIdx.x; i < HW4; i += 256) {
        float4 v = p[i];
        acc += v.x * v.x + v.y * v.y + v.z * v.z + v.w * v.w;
    }
    for (int off = 32; off > 0; off >>= 1)
        acc += __shfl_down(acc, off, 64);
    __shared__ float lds[4];
    const int lane = threadIdx.x & 63, wave = threadIdx.x >> 6;
    if (lane == 0) lds[wave] = acc;
    __syncthreads();
    if (threadIdx.x == 0)
        sumsq[bc] = lds[0] + lds[1] + lds[2] + lds[3];
}

__global__ __launch_bounds__(256) void se_gate_kernel(
    const float* __restrict__ sumsq,
    const float* __restrict__ w_down, const float* __restrict__ b_down,
    const float* __restrict__ w_up, const float* __restrict__ b_up,
    float* __restrict__ gate)
{
    const int b = blockIdx.x;
    const int c = threadIdx.x;
    __shared__ float xs[CC];
    __shared__ float hs[INTERNAL];
    float g = sqrtf(sumsq[b * CC + c]);
    xs[c] = g / (g + 1e-6f);
    __syncthreads();
    if (c < INTERNAL) {
        float a = b_down[c];
        const float* wr = w_down + c * CC;
        for (int k = 0; k < CC; ++k) a += xs[k] * wr[k];
        hs[c] = fmaxf(a, 0.f);
    }
    __syncthreads();
    float a = b_up[c];
    const float* wu = w_up + c * INTERNAL;
    #pragma unroll
    for (int j = 0; j < INTERNAL; ++j) a += hs[j] * wu[j];
    gate[b * CC + c] = 1.f / (1.f + expf(-a));
}

__global__ __launch_bounds__(256) void se_scale_kernel(
    const float* __restrict__ in, const float* __restrict__ gate,
    float* __restrict__ out)
{
    const int bc = blockIdx.x;
    const float gv = gate[bc];
    const float4* pi = reinterpret_cast<const float4*>(in + (size_t)bc * HWSZ);
    float4* po = reinterpret_cast<float4*>(out + (size_t)bc * HWSZ);
    #pragma unroll 4
    for (int i = threadIdx.x; i < HW4; i += 256) {
        float4 v = pi[i];
        v.x *= gv; v.y *= gv; v.z *= gv; v.w *= gv;
        po[i] = v;
    }
}

extern "C" void kernel_launch(void* const* d_in, const int* in_sizes, int n_in,
                              void* d_out, int out_size, void* d_ws, size_t ws_size,
                              hipStream_t stream) {
    const float* inputs = (const float*)d_in[0];   // [B, C, H, W]
    const float* w_down = (const float*)d_in[1];   // [16, 256]
    const float* b_down = (const float*)d_in[2];   // [16]
    const float* w_up   = (const float*)d_in[3];   // [256, 16]
    const float* b_up   = (const float*)d_in[4];   // [256]
    float* out  = (float*)d_out;
    float* pbuf = (float*)d_ws;                    // BB*NBLK floats = 16 KB

    void* args[] = { (void*)&inputs, (void*)&out, (void*)&pbuf,
                     (void*)&w_down, (void*)&b_down, (void*)&w_up, (void*)&b_up };
    hipError_t err = hipLaunchCooperativeKernel(
        reinterpret_cast<void*>(se_fused_kernel),
        dim3(NBLK), dim3(TPB), args, 0, stream);

    if (err != hipSuccess) {
        // deterministic fallback: proven 3-kernel path
        const int nbc = BB * CC;
        float* sumsq = pbuf;               // reuse ws
        float* gate  = sumsq + BB * CC;
        se_sumsq_kernel<<<nbc, 256, 0, stream>>>(inputs, sumsq);
        se_gate_kernel<<<BB, 256, 0, stream>>>(sumsq, w_down, b_down,
                                               w_up, b_up, gate);
        se_scale_kernel<<<nbc, 256, 0, stream>>>(inputs, gate, out);
    }
}